// Round 1
// baseline (100.268 us; speedup 1.0000x reference)
//
#include <hip/hip_runtime.h>
#include <stdint.h>
#include <stddef.h>

#define E_DIM 1024

typedef __bf16 v8bf __attribute__((ext_vector_type(8)));
typedef float v4f __attribute__((ext_vector_type(4)));

__device__ __forceinline__ unsigned short f2bf(float x) {
  unsigned int u = __builtin_bit_cast(unsigned int, x);
  u += 0x7fffu + ((u >> 16) & 1u);
  return (unsigned short)(u >> 16);
}

// fp32 -> bf16, 4 elements per thread, n4 = n/4
__global__ __launch_bounds__(256) void cvt_f32_bf16(const float4* __restrict__ in,
                                                    ushort4* __restrict__ out, int n4) {
  int i = blockIdx.x * 256 + threadIdx.x;
  if (i >= n4) return;
  float4 f = in[i];
  ushort4 u;
  u.x = f2bf(f.x); u.y = f2bf(f.y); u.z = f2bf(f.z); u.w = f2bf(f.w);
  out[i] = u;
}

// in: R x C fp32  ->  out: C x R bf16 (transposed)
__global__ __launch_bounds__(256) void transpose_cvt(const float* __restrict__ in,
                                                     unsigned short* __restrict__ out,
                                                     int R, int C) {
  __shared__ float tile[32][33];
  int nbx = C >> 5;
  int bx = blockIdx.x % nbx;
  int by = blockIdx.x / nbx;
  int tx = threadIdx.x & 31;
  int ty = threadIdx.x >> 5;  // 0..7
#pragma unroll
  for (int i = 0; i < 32; i += 8)
    tile[ty + i][tx] = in[(size_t)(by * 32 + ty + i) * C + bx * 32 + tx];
  __syncthreads();
#pragma unroll
  for (int i = 0; i < 32; i += 8)
    out[(size_t)(bx * 32 + ty + i) * R + by * 32 + tx] = f2bf(tile[tx][ty + i]);
}

// y = W @ x + b, W: R x C fp32, one wave per row
__global__ __launch_bounds__(64) void matvec_bias(const float* __restrict__ W,
                                                  const float* __restrict__ x,
                                                  const float* __restrict__ b,
                                                  float* __restrict__ y, int C) {
  int r = blockIdx.x;
  float s = 0.f;
  for (int c = threadIdx.x; c < C; c += 64)
    s += W[(size_t)r * C + c] * x[c];
#pragma unroll
  for (int off = 32; off; off >>= 1) s += __shfl_down(s, off);
  if (threadIdx.x == 0) y[r] = s + b[r];
}

// C[m][n] = sum_k A[m][k] * B[n][k]  (+ bias[n])
// A: M x K bf16 row-major, Bm: N x K bf16 row-major. 4 waves, 2x2 wave grid.
// OUTBF=1 -> bf16 output to Cb, else fp32 to Cf.
template <int BM, int BN, int BK, int FM, int FN, int OUTBF>
__global__ __launch_bounds__(256) void gemm_bt(const unsigned short* __restrict__ A,
                                               const unsigned short* __restrict__ Bm,
                                               const float* __restrict__ bias,
                                               float* __restrict__ Cf,
                                               unsigned short* __restrict__ Cb,
                                               int M, int N, int K) {
  __shared__ __align__(16) unsigned short Al[BM * BK];
  __shared__ __align__(16) unsigned short Bl[BN * BK];
  constexpr int TMW = BM / 2, TNW = BN / 2;
  const int tid = threadIdx.x;
  const int lane = tid & 63;
  const int wid = tid >> 6;
  const int wr = wid >> 1, wc = wid & 1;
  const int lr = lane & 15;   // row (A) / col (B) within fragment
  const int kg = lane >> 4;   // k-group: 8 contiguous k each
  const int nbn = N / BN;
  const int bm0 = (int)(blockIdx.x / nbn) * BM;
  const int bn0 = (int)(blockIdx.x % nbn) * BN;

  v4f acc[FM][FN];
#pragma unroll
  for (int i = 0; i < FM; ++i)
#pragma unroll
    for (int j = 0; j < FN; ++j) acc[i][j] = 0.f;

  constexpr int ROWB = BK * 2;  // LDS row bytes
  for (int k0 = 0; k0 < K; k0 += BK) {
    // stage A tile: BM x BK bf16, linear LDS, global_load_lds width 16
#pragma unroll
    for (int it = 0; it < (BM * BK * 2) / 4096; ++it) {
      int lbase = it * 4096 + wid * 1024;        // wave-uniform LDS byte base
      int lin = lbase + lane * 16;               // this lane's byte
      int row = lin / ROWB, colb = lin % ROWB;
      const char* g = (const char*)A + ((size_t)(bm0 + row) * K + k0) * 2 + colb;
      __builtin_amdgcn_global_load_lds((__attribute__((address_space(1))) void*)g,
                                       (__attribute__((address_space(3))) void*)((char*)Al + lbase),
                                       16, 0, 0);
    }
#pragma unroll
    for (int it = 0; it < (BN * BK * 2) / 4096; ++it) {
      int lbase = it * 4096 + wid * 1024;
      int lin = lbase + lane * 16;
      int row = lin / ROWB, colb = lin % ROWB;
      const char* g = (const char*)Bm + ((size_t)(bn0 + row) * K + k0) * 2 + colb;
      __builtin_amdgcn_global_load_lds((__attribute__((address_space(1))) void*)g,
                                       (__attribute__((address_space(3))) void*)((char*)Bl + lbase),
                                       16, 0, 0);
    }
    __syncthreads();  // drains vmcnt -> LDS tiles visible

    v8bf af[FM], bfv[FN];
#pragma unroll
    for (int mi = 0; mi < FM; ++mi)
      af[mi] = *reinterpret_cast<const v8bf*>(&Al[(wr * TMW + mi * 16 + lr) * BK + kg * 8]);
#pragma unroll
    for (int ni = 0; ni < FN; ++ni)
      bfv[ni] = *reinterpret_cast<const v8bf*>(&Bl[(wc * TNW + ni * 16 + lr) * BK + kg * 8]);
#pragma unroll
    for (int mi = 0; mi < FM; ++mi)
#pragma unroll
      for (int ni = 0; ni < FN; ++ni)
        acc[mi][ni] = __builtin_amdgcn_mfma_f32_16x16x32_bf16(af[mi], bfv[ni], acc[mi][ni], 0, 0, 0);
    __syncthreads();  // compute done before next stage overwrites LDS
  }

  // epilogue: C/D frag mapping col = lane&15, row = (lane>>4)*4 + reg
#pragma unroll
  for (int ni = 0; ni < FN; ++ni) {
    int col = bn0 + wc * TNW + ni * 16 + lr;
    float bz = bias ? bias[col] : 0.f;
#pragma unroll
    for (int mi = 0; mi < FM; ++mi) {
      int row0 = bm0 + wr * TMW + mi * 16 + kg * 4;
#pragma unroll
      for (int r = 0; r < 4; ++r) {
        float v = acc[mi][ni][r] + bz;
        if (OUTBF) Cb[(size_t)(row0 + r) * N + col] = f2bf(v);
        else       Cf[(size_t)(row0 + r) * N + col] = v;
      }
    }
  }
}

extern "C" void kernel_launch(void* const* d_in, const int* in_sizes, int n_in,
                              void* d_out, int out_size, void* d_ws, size_t ws_size,
                              hipStream_t stream) {
  // inputs: 0 swin_feat, 1 vit_feat, 2 Wq, 3 bq, 4 Wk, 5 bk, 6 Wv, 7 bv,
  //         8 in_proj_w, 9 in_proj_b, 10 Wo, 11 bo
  // softmax over singleton axis == 1  =>  out = ((x@Wv^T+bv)@Wiv^T+biv)@Wo^T+bo
  const float* vit = (const float*)d_in[1];
  const float* Wv  = (const float*)d_in[6];
  const float* bv  = (const float*)d_in[7];
  const float* ipw = (const float*)d_in[8];
  const float* ipb = (const float*)d_in[9];
  const float* Wo  = (const float*)d_in[10];
  const float* bo  = (const float*)d_in[11];
  const float* Wiv = ipw + 2 * E_DIM * E_DIM;   // in_proj_w[2E:3E]
  const float* biv = ipb + 2 * E_DIM;

  char* ws = (char*)d_ws;
  unsigned short* Xb   = (unsigned short*)(ws);             // 16384x512 bf16, 16 MB
  unsigned short* Wivb = (unsigned short*)(ws + 16777216);  // 1024x1024 bf16, 2 MB
  unsigned short* Wob  = (unsigned short*)(ws + 18874368);  // 1024x1024 bf16, 2 MB
  unsigned short* WvTb = (unsigned short*)(ws + 20971520);  // 512x1024 bf16, 1 MB
  unsigned short* Ttb  = (unsigned short*)(ws + 22020096);  // 512x1024 bf16 (T^T)
  unsigned short* Wcb  = (unsigned short*)(ws + 23068672);  // 1024x512 bf16 (Wo Wiv Wv)
  float* b1 = (float*)(ws + 24117248);                      // 1024 fp32
  float* bc = (float*)(ws + 24121344);                      // 1024 fp32

  // 1) convert vit_feat (16384x512), Wiv, Wo to bf16
  cvt_f32_bf16<<<8192, 256, 0, stream>>>((const float4*)vit, (ushort4*)Xb, (16384 * 512) / 4);
  cvt_f32_bf16<<<1024, 256, 0, stream>>>((const float4*)Wiv, (ushort4*)Wivb, (1024 * 1024) / 4);
  cvt_f32_bf16<<<1024, 256, 0, stream>>>((const float4*)Wo, (ushort4*)Wob, (1024 * 1024) / 4);
  // 2) WvT (512x1024) = transpose(Wv 1024x512), bf16
  transpose_cvt<<<(1024 / 32) * (512 / 32), 256, 0, stream>>>(Wv, WvTb, 1024, 512);
  // 3) T^T (512x1024) = WvT @ Wiv^T   [T = Wiv@Wv]
  gemm_bt<64, 64, 32, 2, 2, 1><<<(512 / 64) * (1024 / 64), 256, 0, stream>>>(
      WvTb, Wivb, nullptr, nullptr, Ttb, 512, 1024, 1024);
  // 4) Wc (1024x512) = Wo @ (T^T)^T = Wo@Wiv@Wv
  gemm_bt<64, 64, 32, 2, 2, 1><<<(1024 / 64) * (512 / 64), 256, 0, stream>>>(
      Wob, Ttb, nullptr, nullptr, Wcb, 1024, 512, 1024);
  // 5) bias: b1 = Wiv@bv + biv ; bc = Wo@b1 + bo   (fp32 precision)
  matvec_bias<<<1024, 64, 0, stream>>>(Wiv, bv, biv, b1, 1024);
  matvec_bias<<<1024, 64, 0, stream>>>(Wo, b1, bo, bc, 1024);
  // 6) main: out (16384x1024 fp32) = Xb @ Wc^T + bc
  gemm_bt<128, 128, 32, 4, 4, 0><<<(16384 / 128) * (1024 / 128), 256, 0, stream>>>(
      Xb, Wcb, bc, (float*)d_out, nullptr, 16384, 1024, 512);
}

// Round 3
// 97.485 us; speedup vs baseline: 1.0285x; 1.0285x over previous
//
#include <hip/hip_runtime.h>
#include <stdint.h>
#include <stddef.h>

#define E_DIM 1024

typedef __bf16 v8bf __attribute__((ext_vector_type(8)));
typedef float v4f __attribute__((ext_vector_type(4)));

__device__ __forceinline__ unsigned short f2bf(float x) {
  unsigned int u = __builtin_bit_cast(unsigned int, x);
  u += 0x7fffu + ((u >> 16) & 1u);
  return (unsigned short)(u >> 16);
}

// ---- staging helpers (BK == 32 hardcoded) ----

// fp32 global tile (ROWS x 32) -> bf16 LDS, reg-staged with cvt
template <int ROWS>
__device__ __forceinline__ void stage_f32(const float* __restrict__ G, int g0, int ldg,
                                          int k0, unsigned short* L, int tid) {
#pragma unroll
  for (int p = 0; p < (ROWS * 32) / 1024; ++p) {
    int i4 = p * 256 + tid;       // float4 index within tile
    int row = i4 >> 3;            // 8 float4 per row (BK=32)
    int c4 = i4 & 7;
    float4 f = *reinterpret_cast<const float4*>(G + (size_t)(g0 + row) * ldg + k0 + c4 * 4);
    ushort4 u;
    u.x = f2bf(f.x); u.y = f2bf(f.y); u.z = f2bf(f.z); u.w = f2bf(f.w);
    *reinterpret_cast<ushort4*>(&L[row * 32 + c4 * 4]) = u;
  }
}

// bf16 global tile (ROWS x 32) -> LDS via global_load_lds width 16
template <int ROWS>
__device__ __forceinline__ void stage_bf16(const unsigned short* __restrict__ G, int g0,
                                           int ldg, int k0, unsigned short* L, int tid) {
  int wid = tid >> 6, lane = tid & 63;
#pragma unroll
  for (int it = 0; it < (ROWS * 64) / 4096; ++it) {
    int lbase = it * 4096 + wid * 1024;  // wave-uniform LDS byte base
    int lin = lbase + lane * 16;
    int row = lin >> 6;                  // 64 bytes per LDS row
    int colb = lin & 63;
    const char* g = (const char*)G + ((size_t)(g0 + row) * ldg + k0) * 2 + colb;
    __builtin_amdgcn_global_load_lds((const __attribute__((address_space(1))) void*)g,
                                     (__attribute__((address_space(3))) void*)((char*)L + lbase),
                                     16, 0, 0);
  }
}

// ---- prep1: transpose+cvt Wv (1024x512 f32 -> 512x1024 bf16)  [blocks 0..511]
//             + matvec b1 = Wiv@bv + biv                        [blocks 512..767]
__global__ __launch_bounds__(256) void prep1(const float* __restrict__ Wv,
                                             unsigned short* __restrict__ WvT,
                                             const float* __restrict__ Wiv,
                                             const float* __restrict__ bv,
                                             const float* __restrict__ biv,
                                             float* __restrict__ b1) {
  int bid = blockIdx.x;
  if (bid < 512) {
    // transpose 32x32 tile of Wv (R=1024, C=512)
    __shared__ float tile[32][33];
    const int R = 1024, C = 512;
    int nbx = C >> 5;                  // 16
    int bx = bid % nbx, by = bid / nbx;
    int tx = threadIdx.x & 31, ty = threadIdx.x >> 5;
#pragma unroll
    for (int i = 0; i < 32; i += 8)
      tile[ty + i][tx] = Wv[(size_t)(by * 32 + ty + i) * C + bx * 32 + tx];
    __syncthreads();
#pragma unroll
    for (int i = 0; i < 32; i += 8)
      WvT[(size_t)(bx * 32 + ty + i) * R + by * 32 + tx] = f2bf(tile[tx][ty + i]);
  } else {
    int r = (bid - 512) * 4 + (threadIdx.x >> 6);
    int lane = threadIdx.x & 63;
    float s = 0.f;
    for (int c = lane; c < 1024; c += 64) s += Wiv[(size_t)r * 1024 + c] * bv[c];
#pragma unroll
    for (int off = 32; off; off >>= 1) s += __shfl_down(s, off);
    if (lane == 0) b1[r] = s + biv[r];
  }
}

// ---- generic bt-GEMM: C[m][n] = sum_k A[m][k]*B[n][k] (+bias[n])
// AF32/BF32: that operand is fp32 in global, converted during staging.
// Optional merged matvec for blocks >= ngemm (mvy = mvW@mvx + mvb, 4 rows/block).
template <int BM, int BN, int BK, int FM, int FN, int OUTBF, int AF32, int BF32, int XCDSWZ>
__global__ __launch_bounds__(256) void gemm_bt(const void* __restrict__ Ag,
                                               const void* __restrict__ Bg,
                                               const float* __restrict__ bias,
                                               float* __restrict__ Cf,
                                               unsigned short* __restrict__ Cb,
                                               int M, int N, int K,
                                               const float* __restrict__ mvW,
                                               const float* __restrict__ mvx,
                                               const float* __restrict__ mvb,
                                               float* __restrict__ mvy) {
  static_assert(BK == 32, "BK fixed at 32");
  __shared__ __align__(16) unsigned short Al[BM * BK];
  __shared__ __align__(16) unsigned short Bl[BN * BK];
  const int nbn = N / BN;
  const int ngemm = nbn * (M / BM);
  int bid = blockIdx.x;
  const int tid = threadIdx.x;

  if (bid >= ngemm) {  // merged matvec tail
    int r = (bid - ngemm) * 4 + (tid >> 6);
    int lane = tid & 63;
    float s = 0.f;
    for (int c = lane; c < 1024; c += 64) s += mvW[(size_t)r * 1024 + c] * mvx[c];
#pragma unroll
    for (int off = 32; off; off >>= 1) s += __shfl_down(s, off);
    if (lane == 0) mvy[r] = s + mvb[r];
    return;
  }

  int bm_i, bn_i;
  if (XCDSWZ) {  // cluster all col-blocks of a row-band on one XCD (nbn must be 8)
    int x = bid & 7, j = bid >> 3;
    bm_i = x + ((j >> 3) << 3);
    bn_i = j & 7;
  } else {
    bm_i = bid / nbn;
    bn_i = bid % nbn;
  }
  const int bm0 = bm_i * BM, bn0 = bn_i * BN;

  constexpr int TMW = BM / 2, TNW = BN / 2;
  const int lane = tid & 63;
  const int wid = tid >> 6;
  const int wr = wid >> 1, wc = wid & 1;
  const int lr = lane & 15;
  const int kg = lane >> 4;

  v4f acc[FM][FN];
#pragma unroll
  for (int i = 0; i < FM; ++i)
#pragma unroll
    for (int j = 0; j < FN; ++j) acc[i][j] = 0.f;

  for (int k0 = 0; k0 < K; k0 += BK) {
    if (AF32) stage_f32<BM>((const float*)Ag, bm0, K, k0, Al, tid);
    else      stage_bf16<BM>((const unsigned short*)Ag, bm0, K, k0, Al, tid);
    if (BF32) stage_f32<BN>((const float*)Bg, bn0, K, k0, Bl, tid);
    else      stage_bf16<BN>((const unsigned short*)Bg, bn0, K, k0, Bl, tid);
    __syncthreads();  // drains vmcnt (gload_lds) + lgkmcnt (ds_write)

    v8bf af[FM], bfv[FN];
#pragma unroll
    for (int mi = 0; mi < FM; ++mi)
      af[mi] = *reinterpret_cast<const v8bf*>(&Al[(wr * TMW + mi * 16 + lr) * BK + kg * 8]);
#pragma unroll
    for (int ni = 0; ni < FN; ++ni)
      bfv[ni] = *reinterpret_cast<const v8bf*>(&Bl[(wc * TNW + ni * 16 + lr) * BK + kg * 8]);
#pragma unroll
    for (int mi = 0; mi < FM; ++mi)
#pragma unroll
      for (int ni = 0; ni < FN; ++ni)
        acc[mi][ni] = __builtin_amdgcn_mfma_f32_16x16x32_bf16(af[mi], bfv[ni], acc[mi][ni], 0, 0, 0);
    __syncthreads();
  }

  // epilogue: C/D frag mapping col = lane&15, row = (lane>>4)*4 + reg
#pragma unroll
  for (int ni = 0; ni < FN; ++ni) {
    int col = bn0 + wc * TNW + ni * 16 + lr;
    float bz = bias ? bias[col] : 0.f;
#pragma unroll
    for (int mi = 0; mi < FM; ++mi) {
      int row0 = bm0 + wr * TMW + mi * 16 + kg * 4;
#pragma unroll
      for (int r = 0; r < 4; ++r) {
        float v = acc[mi][ni][r] + bz;
        if (OUTBF) Cb[(size_t)(row0 + r) * N + col] = f2bf(v);
        else       Cf[(size_t)(row0 + r) * N + col] = v;
      }
    }
  }
}

extern "C" void kernel_launch(void* const* d_in, const int* in_sizes, int n_in,
                              void* d_out, int out_size, void* d_ws, size_t ws_size,
                              hipStream_t stream) {
  // softmax over singleton axis == 1  =>  out = ((x@Wv^T+bv)@Wiv^T+biv)@Wo^T+bo
  //                                           = x @ (Wo·Wiv·Wv)^T + [Wo·(Wiv·bv+biv)+bo]
  const float* vit = (const float*)d_in[1];
  const float* Wv  = (const float*)d_in[6];
  const float* bv  = (const float*)d_in[7];
  const float* ipw = (const float*)d_in[8];
  const float* ipb = (const float*)d_in[9];
  const float* Wo  = (const float*)d_in[10];
  const float* bo  = (const float*)d_in[11];
  const float* Wiv = ipw + 2 * E_DIM * E_DIM;
  const float* biv = ipb + 2 * E_DIM;

  char* ws = (char*)d_ws;
  unsigned short* WvTb = (unsigned short*)(ws);                // 512x1024 bf16, 1 MB
  unsigned short* Ttb  = (unsigned short*)(ws + (1 << 20));    // 512x1024 bf16 (T^T)
  unsigned short* Wcb  = (unsigned short*)(ws + (2 << 20));    // 1024x512 bf16
  float* b1 = (float*)(ws + (3 << 20));
  float* bc = (float*)(ws + (3 << 20) + 4096);

  // K1: transpose+cvt Wv -> WvT  ||  b1 = Wiv@bv + biv
  prep1<<<768, 256, 0, stream>>>(Wv, WvTb, Wiv, bv, biv, b1);

  // K2: T^T (512x1024) = WvT @ Wiv^T (B staged f32->bf16)  ||  bc = Wo@b1 + bo
  gemm_bt<64, 64, 32, 2, 2, 1, 0, 1, 0><<<128 + 256, 256, 0, stream>>>(
      WvTb, Wiv, nullptr, nullptr, Ttb, 512, 1024, 1024, Wo, b1, bo, bc);

  // K3: Wc (1024x512) = Wo @ T  (A staged f32->bf16, B = T^T bf16)
  gemm_bt<64, 64, 32, 2, 2, 1, 1, 0, 0><<<128, 256, 0, stream>>>(
      Wo, Ttb, nullptr, nullptr, Wcb, 1024, 512, 1024, nullptr, nullptr, nullptr, nullptr);

  // K4: out (16384x1024 f32) = vit @ Wc^T + bc  (A staged f32->bf16, XCD row-band swizzle)
  gemm_bt<128, 128, 32, 4, 4, 0, 1, 0, 1><<<1024, 256, 0, stream>>>(
      vit, Wcb, bc, (float*)d_out, nullptr, 16384, 1024, 512,
      nullptr, nullptr, nullptr, nullptr);
}

// Round 4
// 83.634 us; speedup vs baseline: 1.1989x; 1.1656x over previous
//
#include <hip/hip_runtime.h>
#include <stdint.h>
#include <stddef.h>

#define E_DIM 1024

typedef __bf16 v8bf __attribute__((ext_vector_type(8)));
typedef float v4f __attribute__((ext_vector_type(4)));

__device__ __forceinline__ unsigned short f2bf(float x) {
  unsigned int u = __builtin_bit_cast(unsigned int, x);
  u += 0x7fffu + ((u >> 16) & 1u);
  return (unsigned short)(u >> 16);
}

// XOR swizzle for LDS tiles: only needed when row-stride RB >= 128B (else the
// (row&1, lane>>4) bits already give the 8 distinct 16B bank-phases = b128 floor).
template <int RB>
__device__ __forceinline__ int swz(int r, int c) {
  if constexpr (RB >= 128) return c ^ ((r & 7) << 4);
  else return c;
}

// Stage a ROWS x BK tile (fp32 or bf16) into LDS via global_load_lds (async).
// LDS dest is linear; the SOURCE address is pre-swizzled so swizzled reads see
// the right data (rule: both-sides-or-neither).
template <int ROWS, int BK, int F32>
__device__ __forceinline__ void stage(const char* __restrict__ G, int g0, int ldg,
                                      int k0, char* L, int tid) {
  constexpr int ESZ = F32 ? 4 : 2;
  constexpr int RB = BK * ESZ;
  constexpr int ITERS = (ROWS * RB) / 4096;
  const int wid = tid >> 6, lane = tid & 63;
#pragma unroll
  for (int it = 0; it < ITERS; ++it) {
    int lbase = it * 4096 + wid * 1024;   // wave-uniform LDS byte base
    int lin = lbase + lane * 16;
    int r = lin / RB, cb = lin % RB;      // RB is a power of two
    int gcb = swz<RB>(r, cb);
    const char* g = G + ((size_t)(g0 + r) * ldg + k0) * ESZ + gcb;
    __builtin_amdgcn_global_load_lds((const __attribute__((address_space(1))) void*)g,
                                     (__attribute__((address_space(3))) void*)(L + lbase),
                                     16, 0, 0);
  }
}

// Read an 8-elem bf16 fragment from an fp32 LDS tile (cvt in regs).
// kelem*4 is a multiple of 32 -> second 16B block is (o ^ 16).
template <int RB>
__device__ __forceinline__ v8bf fragA_f32(const char* L, int r, int kelem) {
  const char* p = L + r * RB;
  int o = swz<RB>(r, kelem * 4);
  float4 lo = *(const float4*)(p + o);
  float4 hi = *(const float4*)(p + (o ^ 16));
  v8bf f;
  f[0] = (__bf16)lo.x; f[1] = (__bf16)lo.y; f[2] = (__bf16)lo.z; f[3] = (__bf16)lo.w;
  f[4] = (__bf16)hi.x; f[5] = (__bf16)hi.y; f[6] = (__bf16)hi.z; f[7] = (__bf16)hi.w;
  return f;
}

template <int RB>
__device__ __forceinline__ v8bf frag_bf16(const char* L, int r, int kelem) {
  int o = swz<RB>(r, kelem * 2);
  return *(const v8bf*)(L + r * RB + o);
}

// ---- prep1: transpose+cvt Wv (1024x512 f32 -> 512x1024 bf16)  [blocks 0..511]
//             + matvec b1 = Wiv@bv + biv                        [blocks 512..767]
__global__ __launch_bounds__(256) void prep1(const float* __restrict__ Wv,
                                             unsigned short* __restrict__ WvT,
                                             const float* __restrict__ Wiv,
                                             const float* __restrict__ bv,
                                             const float* __restrict__ biv,
                                             float* __restrict__ b1) {
  int bid = blockIdx.x;
  if (bid < 512) {
    __shared__ float tile[32][33];
    const int R = 1024, C = 512;
    int nbx = C >> 5;
    int bx = bid % nbx, by = bid / nbx;
    int tx = threadIdx.x & 31, ty = threadIdx.x >> 5;
#pragma unroll
    for (int i = 0; i < 32; i += 8)
      tile[ty + i][tx] = Wv[(size_t)(by * 32 + ty + i) * C + bx * 32 + tx];
    __syncthreads();
#pragma unroll
    for (int i = 0; i < 32; i += 8)
      WvT[(size_t)(bx * 32 + ty + i) * R + by * 32 + tx] = f2bf(tile[tx][ty + i]);
  } else {
    int r = (bid - 512) * 4 + (threadIdx.x >> 6);
    int lane = threadIdx.x & 63;
    float s = 0.f;
    for (int c = lane; c < 1024; c += 64) s += Wiv[(size_t)r * 1024 + c] * bv[c];
#pragma unroll
    for (int off = 32; off; off >>= 1) s += __shfl_down(s, off);
    if (lane == 0) b1[r] = s + biv[r];
  }
}

// ---- bt-GEMM: C[m][n] = sum_k A[m][k]*B[n][k] (+bias[n])
// AF32/BF32: operand is fp32 in global, staged fp32 into LDS, cvt on frag read.
// Optional merged matvec tail (4 rows/block over 1024 cols).
template <int BM, int BN, int BK, int FM, int FN, int OUTBF, int AF32, int BF32, int XCDSWZ>
__global__ __launch_bounds__(256) void gemm_bt(const void* __restrict__ Ag,
                                               const void* __restrict__ Bg,
                                               const float* __restrict__ bias,
                                               float* __restrict__ Cf,
                                               unsigned short* __restrict__ Cb,
                                               int M, int N, int K,
                                               const float* __restrict__ mvW,
                                               const float* __restrict__ mvx,
                                               const float* __restrict__ mvb,
                                               float* __restrict__ mvy) {
  constexpr int RBA = BK * (AF32 ? 4 : 2);
  constexpr int RBB = BK * (BF32 ? 4 : 2);
  __shared__ __align__(16) char Al[BM * RBA];
  __shared__ __align__(16) char Bl[BN * RBB];
  const int nbn = N / BN;
  const int ngemm = nbn * (M / BM);
  int bid = blockIdx.x;
  const int tid = threadIdx.x;

  if (bid >= ngemm) {  // merged matvec tail
    int r = (bid - ngemm) * 4 + (tid >> 6);
    int lane = tid & 63;
    float s = 0.f;
    for (int c = lane; c < 1024; c += 64) s += mvW[(size_t)r * 1024 + c] * mvx[c];
#pragma unroll
    for (int off = 32; off; off >>= 1) s += __shfl_down(s, off);
    if (lane == 0) mvy[r] = s + mvb[r];
    return;
  }

  int bm_i, bn_i;
  if (XCDSWZ) {  // all 8 col-blocks of a row-band on one XCD (nbn == 8)
    int x = bid & 7, j = bid >> 3;
    bm_i = x + ((j >> 3) << 3);
    bn_i = j & 7;
  } else {
    bm_i = bid / nbn;
    bn_i = bid % nbn;
  }
  const int bm0 = bm_i * BM, bn0 = bn_i * BN;

  constexpr int TMW = BM / 2, TNW = BN / 2;
  const int lane = tid & 63;
  const int wid = tid >> 6;
  const int wr = wid >> 1, wc = wid & 1;
  const int lr = lane & 15;
  const int kg = lane >> 4;

  v4f acc[FM][FN];
#pragma unroll
  for (int i = 0; i < FM; ++i)
#pragma unroll
    for (int j = 0; j < FN; ++j) acc[i][j] = 0.f;

  for (int k0 = 0; k0 < K; k0 += BK) {
    stage<BM, BK, AF32>((const char*)Ag, bm0, K, k0, Al, tid);
    stage<BN, BK, BF32>((const char*)Bg, bn0, K, k0, Bl, tid);
    __syncthreads();  // drains vmcnt -> tiles visible

#pragma unroll
    for (int kk = 0; kk < BK / 32; ++kk) {
      const int ke = kk * 32 + kg * 8;
      v8bf a[FM], b[FN];
#pragma unroll
      for (int mi = 0; mi < FM; ++mi) {
        int ra = wr * TMW + mi * 16 + lr;
        if constexpr (AF32) a[mi] = fragA_f32<RBA>(Al, ra, ke);
        else                a[mi] = frag_bf16<RBA>(Al, ra, ke);
      }
#pragma unroll
      for (int ni = 0; ni < FN; ++ni) {
        int rb = wc * TNW + ni * 16 + lr;
        if constexpr (BF32) b[ni] = fragA_f32<RBB>(Bl, rb, ke);
        else                b[ni] = frag_bf16<RBB>(Bl, rb, ke);
      }
#pragma unroll
      for (int mi = 0; mi < FM; ++mi)
#pragma unroll
        for (int ni = 0; ni < FN; ++ni)
          acc[mi][ni] = __builtin_amdgcn_mfma_f32_16x16x32_bf16(a[mi], b[ni], acc[mi][ni], 0, 0, 0);
    }
    __syncthreads();  // compute done before next stage overwrites LDS
  }

  // epilogue: C/D frag mapping col = lane&15, row = (lane>>4)*4 + reg
#pragma unroll
  for (int ni = 0; ni < FN; ++ni) {
    int col = bn0 + wc * TNW + ni * 16 + lr;
    float bz = bias ? bias[col] : 0.f;
#pragma unroll
    for (int mi = 0; mi < FM; ++mi) {
      int row0 = bm0 + wr * TMW + mi * 16 + kg * 4;
#pragma unroll
      for (int r = 0; r < 4; ++r) {
        float v = acc[mi][ni][r] + bz;
        if (OUTBF) Cb[(size_t)(row0 + r) * N + col] = f2bf(v);
        else       Cf[(size_t)(row0 + r) * N + col] = v;
      }
    }
  }
}

extern "C" void kernel_launch(void* const* d_in, const int* in_sizes, int n_in,
                              void* d_out, int out_size, void* d_ws, size_t ws_size,
                              hipStream_t stream) {
  // softmax over singleton axis == 1  =>  out = x @ (Wo·Wiv·Wv)^T + [Wo·(Wiv·bv+biv)+bo]
  const float* vit = (const float*)d_in[1];
  const float* Wv  = (const float*)d_in[6];
  const float* bv  = (const float*)d_in[7];
  const float* ipw = (const float*)d_in[8];
  const float* ipb = (const float*)d_in[9];
  const float* Wo  = (const float*)d_in[10];
  const float* bo  = (const float*)d_in[11];
  const float* Wiv = ipw + 2 * E_DIM * E_DIM;
  const float* biv = ipb + 2 * E_DIM;

  char* ws = (char*)d_ws;
  unsigned short* WvTb = (unsigned short*)(ws);              // 512x1024 bf16
  unsigned short* Ttb  = (unsigned short*)(ws + (1 << 20));  // 512x1024 bf16 (T^T)
  unsigned short* Wcb  = (unsigned short*)(ws + (2 << 20));  // 1024x512 bf16
  float* b1 = (float*)(ws + (3 << 20));
  float* bc = (float*)(ws + (3 << 20) + 4096);

  // K1: transpose+cvt Wv -> WvT  ||  b1 = Wiv@bv + biv
  prep1<<<768, 256, 0, stream>>>(Wv, WvTb, Wiv, bv, biv, b1);

  // K2: T^T (512x1024) = WvT @ Wiv^T (B fp32-in-LDS), BK=64  ||  bc = Wo@b1 + bo
  gemm_bt<64, 64, 64, 2, 2, 1, 0, 1, 0><<<128 + 256, 256, 0, stream>>>(
      WvTb, Wiv, nullptr, nullptr, Ttb, 512, 1024, 1024, Wo, b1, bo, bc);

  // K3: Wc (1024x512) = Wo @ T (A fp32-in-LDS), BK=64
  gemm_bt<64, 64, 64, 2, 2, 1, 1, 0, 0><<<128, 256, 0, stream>>>(
      Wo, Ttb, nullptr, nullptr, Wcb, 1024, 512, 1024,
      nullptr, nullptr, nullptr, nullptr);

  // K4: out (16384x1024 f32) = vit @ Wc^T + bc (A fp32-in-LDS, XCD swizzle)
  gemm_bt<128, 128, 32, 4, 4, 0, 1, 0, 1><<<1024, 256, 0, stream>>>(
      vit, Wcb, bc, (float*)d_out, nullptr, 16384, 1024, 512,
      nullptr, nullptr, nullptr, nullptr);
}

// Round 5
// 67.298 us; speedup vs baseline: 1.4899x; 1.2427x over previous
//
#include <hip/hip_runtime.h>
#include <stdint.h>
#include <stddef.h>

#define E_DIM 1024

typedef __bf16 v8bf __attribute__((ext_vector_type(8)));
typedef float v4f __attribute__((ext_vector_type(4)));

__device__ __forceinline__ unsigned short f2bf(float x) {
  unsigned int u = __builtin_bit_cast(unsigned int, x);
  u += 0x7fffu + ((u >> 16) & 1u);
  return (unsigned short)(u >> 16);
}

// XOR swizzle for LDS tiles: needed when row-stride RB >= 128B (else the
// natural (row, 16B-chunk) bits already spread banks to the b128 floor).
template <int RB>
__device__ __forceinline__ int swz(int r, int c) {
  if constexpr (RB >= 128) return c ^ ((r & 7) << 4);
  else return c;
}

// Stage a ROWS x BK tile (fp32 or bf16) into LDS via global_load_lds (async).
// LDS dest linear; SOURCE address pre-swizzled (both-sides-or-neither rule).
template <int ROWS, int BK, int F32>
__device__ __forceinline__ void stage(const char* __restrict__ G, int g0, int ldg,
                                      int k0, char* L, int tid) {
  constexpr int ESZ = F32 ? 4 : 2;
  constexpr int RB = BK * ESZ;
  constexpr int ITERS = (ROWS * RB) / 4096;
  const int wid = tid >> 6, lane = tid & 63;
#pragma unroll
  for (int it = 0; it < ITERS; ++it) {
    int lbase = it * 4096 + wid * 1024;   // wave-uniform LDS byte base
    int lin = lbase + lane * 16;
    int r = lin / RB, cb = lin % RB;
    int gcb = swz<RB>(r, cb);
    const char* g = G + ((size_t)(g0 + r) * ldg + k0) * ESZ + gcb;
    __builtin_amdgcn_global_load_lds((const __attribute__((address_space(1))) void*)g,
                                     (__attribute__((address_space(3))) void*)(L + lbase),
                                     16, 0, 0);
  }
}

// 8-elem bf16 fragment from an fp32 LDS tile (cvt in regs). kelem*4 % 32 == 0.
template <int RB>
__device__ __forceinline__ v8bf fragA_f32(const char* L, int r, int kelem) {
  const char* p = L + r * RB;
  int o = swz<RB>(r, kelem * 4);
  float4 lo = *(const float4*)(p + o);
  float4 hi = *(const float4*)(p + (o ^ 16));
  v8bf f;
  f[0] = (__bf16)lo.x; f[1] = (__bf16)lo.y; f[2] = (__bf16)lo.z; f[3] = (__bf16)lo.w;
  f[4] = (__bf16)hi.x; f[5] = (__bf16)hi.y; f[6] = (__bf16)hi.z; f[7] = (__bf16)hi.w;
  return f;
}

template <int RB>
__device__ __forceinline__ v8bf frag_bf16(const char* L, int r, int kelem) {
  int o = swz<RB>(r, kelem * 2);
  return *(const v8bf*)(L + r * RB + o);
}

// one K-tile of MFMA work from LDS buffers
template <int BM, int BN, int BK, int FM, int FN, int AF32, int BF32>
__device__ __forceinline__ void compute_tile(const char* Al, const char* Bl,
                                             v4f (&acc)[FM][FN],
                                             int wr, int wc, int lr, int kg) {
  constexpr int RBA = BK * (AF32 ? 4 : 2);
  constexpr int RBB = BK * (BF32 ? 4 : 2);
  constexpr int TMW = BM / 2, TNW = BN / 2;
#pragma unroll
  for (int kk = 0; kk < BK / 32; ++kk) {
    const int ke = kk * 32 + kg * 8;
    v8bf a[FM], b[FN];
#pragma unroll
    for (int mi = 0; mi < FM; ++mi) {
      int ra = wr * TMW + mi * 16 + lr;
      if constexpr (AF32) a[mi] = fragA_f32<RBA>(Al, ra, ke);
      else                a[mi] = frag_bf16<RBA>(Al, ra, ke);
    }
#pragma unroll
    for (int ni = 0; ni < FN; ++ni) {
      int rb = wc * TNW + ni * 16 + lr;
      if constexpr (BF32) b[ni] = fragA_f32<RBB>(Bl, rb, ke);
      else                b[ni] = frag_bf16<RBB>(Bl, rb, ke);
    }
#pragma unroll
    for (int mi = 0; mi < FM; ++mi)
#pragma unroll
      for (int ni = 0; ni < FN; ++ni)
        acc[mi][ni] = __builtin_amdgcn_mfma_f32_16x16x32_bf16(a[mi], b[ni], acc[mi][ni], 0, 0, 0);
  }
}

// ---- prep1: transpose+cvt Wv (1024x512 f32 -> 512x1024 bf16)  [blocks 0..511]
//             + matvec b1 = Wiv@bv + biv                        [blocks 512..767]
__global__ __launch_bounds__(256) void prep1(const float* __restrict__ Wv,
                                             unsigned short* __restrict__ WvT,
                                             const float* __restrict__ Wiv,
                                             const float* __restrict__ bv,
                                             const float* __restrict__ biv,
                                             float* __restrict__ b1) {
  int bid = blockIdx.x;
  if (bid < 512) {
    __shared__ float tile[32][33];
    const int R = 1024, C = 512;
    int nbx = C >> 5;
    int bx = bid % nbx, by = bid / nbx;
    int tx = threadIdx.x & 31, ty = threadIdx.x >> 5;
#pragma unroll
    for (int i = 0; i < 32; i += 8)
      tile[ty + i][tx] = Wv[(size_t)(by * 32 + ty + i) * C + bx * 32 + tx];
    __syncthreads();
#pragma unroll
    for (int i = 0; i < 32; i += 8)
      WvT[(size_t)(bx * 32 + ty + i) * R + by * 32 + tx] = f2bf(tile[tx][ty + i]);
  } else {
    int r = (bid - 512) * 4 + (threadIdx.x >> 6);
    int lane = threadIdx.x & 63;
    float s = 0.f;
    for (int c = lane; c < 1024; c += 64) s += Wiv[(size_t)r * 1024 + c] * bv[c];
#pragma unroll
    for (int off = 32; off; off >>= 1) s += __shfl_down(s, off);
    if (lane == 0) b1[r] = s + biv[r];
  }
}

// ---- bt-GEMM with T3-min prefetch double-buffer:
// issue next tile's global_load_lds BEFORE computing current; single barrier
// per K-step drains the prefetch AFTER compute (latency overlapped).
// Requires K/BK even.
template <int BM, int BN, int BK, int FM, int FN, int OUTBF, int AF32, int BF32, int XCDSWZ>
__global__ __launch_bounds__(256) void gemm_bt(const void* __restrict__ Ag,
                                               const void* __restrict__ Bg,
                                               const float* __restrict__ bias,
                                               float* __restrict__ Cf,
                                               unsigned short* __restrict__ Cb,
                                               int M, int N, int K,
                                               const float* __restrict__ mvW,
                                               const float* __restrict__ mvx,
                                               const float* __restrict__ mvb,
                                               float* __restrict__ mvy) {
  constexpr int RBA = BK * (AF32 ? 4 : 2);
  constexpr int RBB = BK * (BF32 ? 4 : 2);
  __shared__ __align__(16) char Al0[BM * RBA];
  __shared__ __align__(16) char Al1[BM * RBA];
  __shared__ __align__(16) char Bl0[BN * RBB];
  __shared__ __align__(16) char Bl1[BN * RBB];
  const int nbn = N / BN;
  const int ngemm = nbn * (M / BM);
  int bid = blockIdx.x;
  const int tid = threadIdx.x;

  if (bid >= ngemm) {  // merged matvec tail
    int r = (bid - ngemm) * 4 + (tid >> 6);
    int lane = tid & 63;
    float s = 0.f;
    for (int c = lane; c < 1024; c += 64) s += mvW[(size_t)r * 1024 + c] * mvx[c];
#pragma unroll
    for (int off = 32; off; off >>= 1) s += __shfl_down(s, off);
    if (lane == 0) mvy[r] = s + mvb[r];
    return;
  }

  int bm_i, bn_i;
  if (XCDSWZ) {  // all 8 col-blocks of a row-band on one XCD (nbn == 8)
    int x = bid & 7, j = bid >> 3;
    bm_i = x + ((j >> 3) << 3);
    bn_i = j & 7;
  } else {
    bm_i = bid / nbn;
    bn_i = bid % nbn;
  }
  const int bm0 = bm_i * BM, bn0 = bn_i * BN;

  constexpr int TMW = BM / 2, TNW = BN / 2;
  const int lane = tid & 63;
  const int wid = tid >> 6;
  const int wr = wid >> 1, wc = wid & 1;
  const int lr = lane & 15;
  const int kg = lane >> 4;
  const char* Ac = (const char*)Ag;
  const char* Bc = (const char*)Bg;

  v4f acc[FM][FN];
#pragma unroll
  for (int i = 0; i < FM; ++i)
#pragma unroll
    for (int j = 0; j < FN; ++j) acc[i][j] = 0.f;

  const int NT = K / BK;  // even
  stage<BM, BK, AF32>(Ac, bm0, K, 0, Al0, tid);
  stage<BN, BK, BF32>(Bc, bn0, K, 0, Bl0, tid);
  __syncthreads();

  for (int t = 0; t < NT; t += 2) {
    if (t + 1 < NT) {
      stage<BM, BK, AF32>(Ac, bm0, K, (t + 1) * BK, Al1, tid);
      stage<BN, BK, BF32>(Bc, bn0, K, (t + 1) * BK, Bl1, tid);
    }
    __builtin_amdgcn_sched_barrier(0);  // keep prefetch issues before compute
    compute_tile<BM, BN, BK, FM, FN, AF32, BF32>(Al0, Bl0, acc, wr, wc, lr, kg);
    __syncthreads();  // drains prefetch vmcnt after compute

    if (t + 2 < NT) {
      stage<BM, BK, AF32>(Ac, bm0, K, (t + 2) * BK, Al0, tid);
      stage<BN, BK, BF32>(Bc, bn0, K, (t + 2) * BK, Bl0, tid);
    }
    __builtin_amdgcn_sched_barrier(0);
    compute_tile<BM, BN, BK, FM, FN, AF32, BF32>(Al1, Bl1, acc, wr, wc, lr, kg);
    __syncthreads();
  }

  // epilogue: C/D frag mapping col = lane&15, row = (lane>>4)*4 + reg
#pragma unroll
  for (int ni = 0; ni < FN; ++ni) {
    int col = bn0 + wc * TNW + ni * 16 + lr;
    float bz = bias ? bias[col] : 0.f;
#pragma unroll
    for (int mi = 0; mi < FM; ++mi) {
      int row0 = bm0 + wr * TMW + mi * 16 + kg * 4;
#pragma unroll
      for (int r = 0; r < 4; ++r) {
        float v = acc[mi][ni][r] + bz;
        if (OUTBF) Cb[(size_t)(row0 + r) * N + col] = f2bf(v);
        else       Cf[(size_t)(row0 + r) * N + col] = v;
      }
    }
  }
}

extern "C" void kernel_launch(void* const* d_in, const int* in_sizes, int n_in,
                              void* d_out, int out_size, void* d_ws, size_t ws_size,
                              hipStream_t stream) {
  // softmax over singleton axis == 1  =>  out = x @ (Wo·Wiv·Wv)^T + [Wo·(Wiv·bv+biv)+bo]
  const float* vit = (const float*)d_in[1];
  const float* Wv  = (const float*)d_in[6];
  const float* bv  = (const float*)d_in[7];
  const float* ipw = (const float*)d_in[8];
  const float* ipb = (const float*)d_in[9];
  const float* Wo  = (const float*)d_in[10];
  const float* bo  = (const float*)d_in[11];
  const float* Wiv = ipw + 2 * E_DIM * E_DIM;
  const float* biv = ipb + 2 * E_DIM;

  char* ws = (char*)d_ws;
  unsigned short* WvTb = (unsigned short*)(ws);              // 512x1024 bf16
  unsigned short* Ttb  = (unsigned short*)(ws + (1 << 20));  // 512x1024 bf16 (T^T)
  unsigned short* Wcb  = (unsigned short*)(ws + (2 << 20));  // 1024x512 bf16
  float* b1 = (float*)(ws + (3 << 20));
  float* bc = (float*)(ws + (3 << 20) + 4096);

  // K1: transpose+cvt Wv -> WvT  ||  b1 = Wiv@bv + biv
  prep1<<<768, 256, 0, stream>>>(Wv, WvTb, Wiv, bv, biv, b1);

  // K2: T^T (512x1024) = WvT @ Wiv^T (B fp32-in-LDS), BK=64  ||  bc = Wo@b1 + bo
  gemm_bt<64, 64, 64, 2, 2, 1, 0, 1, 0><<<128 + 256, 256, 0, stream>>>(
      WvTb, Wiv, nullptr, nullptr, Ttb, 512, 1024, 1024, Wo, b1, bo, bc);

  // K3: Wc (1024x512) = Wo @ T (A fp32-in-LDS), BK=64
  gemm_bt<64, 64, 64, 2, 2, 1, 1, 0, 0><<<128, 256, 0, stream>>>(
      Wo, Ttb, nullptr, nullptr, Wcb, 1024, 512, 1024,
      nullptr, nullptr, nullptr, nullptr);

  // K4: out (16384x1024 f32) = vit @ Wc^T + bc (A fp32-in-LDS, XCD swizzle)
  gemm_bt<128, 128, 32, 4, 4, 0, 1, 0, 1><<<1024, 256, 0, stream>>>(
      vit, Wcb, bc, (float*)d_out, nullptr, 16384, 1024, 512,
      nullptr, nullptr, nullptr, nullptr);
}